// Round 13
// baseline (555.078 us; speedup 1.0000x reference)
//
#include <hip/hip_runtime.h>
#include <hip/hip_bf16.h>
#include <hip/hip_fp16.h>

typedef unsigned short ushortT;
typedef _Float16 half8 __attribute__((ext_vector_type(8)));
typedef float f32x4 __attribute__((ext_vector_type(4)));

#define N_ROWS   32768
#define DIM      512
#define K_CODES  8192
#define BETA     0.01f

// d_out layout (floats): [quantized 16777216][loss 1][indices-as-float 32768]
#define LOSS_OFF 16777216
#define IDX_OFF  16777217

// d_out-as-scratch (float offsets). Audited map (all disjoint):
//   xh      [0,        8388608)   32768*512 halves
//   eh      [8388608,  10485760)  8192*512 halves
//   gCode   [10485760, 11010048)  32768*16 u32 (packed score<<16|code)
//   gCnt    [11010048, 11042816)  32768 u32
//   fixmin  [11042816, 11108352)  32768 u64 (8B-aligned)
//   fixlist [11108352, 11173888)  65536 i32 (KSPLIT=2: <=2 entries/row)
#define SC_XH_F      0
#define SC_EH_F      8388608
#define SC_GCODE_F   10485760
#define SC_GCNT_F    11010048
#define SC_FIXMIN_F  11042816
#define SC_FIXLIST_F 11108352

// d_ws layout (4-byte units): xx[32768] | idx[32768] | partial[8192] | cnt[1]
#define WS_XX_OFF     0
#define WS_IDX_OFF    32768
#define WS_PART_OFF   65536
#define WS_CNT_OFF    73728

#define FLT_BIG 3.402823466e+38f
#define W_ACC   0.08192f   // 1.6e-4 (s-domain window) * 512 (acc scale = 1024/2)
#define W_FILT  0.09192f   // W_ACC + fp16-packing slack
#define GCAP    16

typedef __attribute__((address_space(1))) const unsigned int GUI;
typedef __attribute__((address_space(3))) unsigned int LUI;
__device__ __forceinline__ void gload16(const void* g, void* l) {
    __builtin_amdgcn_global_load_lds((GUI*)g, (LUI*)l, 16, 0, 0);
}

// ---------------------------------------------------------------- init
// One dispatch replacing 3 hipMemsetAsync: gCnt=0, fixmin=~0, fixcnt=0.
__global__ __launch_bounds__(256) void vq_init(unsigned* __restrict__ gCnt,
                                               unsigned long long* __restrict__ fixmin,
                                               int* __restrict__ fixcnt) {
    const int i = blockIdx.x * 256 + threadIdx.x;   // grid 128 -> 32768 threads
    gCnt[i] = 0u;
    fixmin[i] = ~0ULL;
    if (i == 0) *fixcnt = 0;
}

// ---------------------------------------------------------------- prep (+xx fused)
// xh = fp16(x); eh = fp16(1024*e). Blocks < 8192 also compute xx[row] with the
// numpy-pairwise-exact tree (proven round 3) from the already-loaded x values.
__global__ __launch_bounds__(256) void vq_prep(const float* __restrict__ x,
                                               const float* __restrict__ cb,
                                               ushortT* __restrict__ xh,
                                               ushortT* __restrict__ eh,
                                               float* __restrict__ xx) {
    __shared__ float l[4][512];
    const size_t gid = (size_t)blockIdx.x * 256 + threadIdx.x;
    const size_t off8 = gid * 8;
    const bool isX = (blockIdx.x < 8192);
    const float* src;
    ushortT* dst;
    float sc;
    if (isX) { src = x + off8; dst = xh + off8; sc = 1.0f; }
    else { size_t o = off8 - 16777216UL; src = cb + o; dst = eh + o; sc = 1024.0f; }
    float4 v0 = *reinterpret_cast<const float4*>(src);
    float4 v1 = *reinterpret_cast<const float4*>(src + 4);
    union { ushortT s[8]; uint4 v; } u;
    u.s[0] = __half_as_ushort(__float2half(v0.x * sc));
    u.s[1] = __half_as_ushort(__float2half(v0.y * sc));
    u.s[2] = __half_as_ushort(__float2half(v0.z * sc));
    u.s[3] = __half_as_ushort(__float2half(v0.w * sc));
    u.s[4] = __half_as_ushort(__float2half(v1.x * sc));
    u.s[5] = __half_as_ushort(__float2half(v1.y * sc));
    u.s[6] = __half_as_ushort(__float2half(v1.z * sc));
    u.s[7] = __half_as_ushort(__float2half(v1.w * sc));
    *reinterpret_cast<uint4*>(dst) = u.v;
    if (isX) {
        const int wave = threadIdx.x >> 6;
        const int lane = threadIdx.x & 63;
        float4 q0 = make_float4(v0.x * v0.x, v0.y * v0.y, v0.z * v0.z, v0.w * v0.w);
        float4 q1 = make_float4(v1.x * v1.x, v1.y * v1.y, v1.z * v1.z, v1.w * v1.w);
        *reinterpret_cast<float4*>(&l[wave][lane * 8]) = q0;
        *reinterpret_cast<float4*>(&l[wave][lane * 8 + 4]) = q1;
        __syncthreads();
        if (lane == 0) {
            float B[4];
#pragma unroll
            for (int q = 0; q < 4; ++q) {
                const float* a = &l[wave][q * 128];
                float r0 = a[0], r1 = a[1], r2 = a[2], r3 = a[3];
                float r4 = a[4], r5 = a[5], r6 = a[6], r7 = a[7];
                for (int i = 8; i < 128; i += 8) {
                    r0 += a[i + 0]; r1 += a[i + 1]; r2 += a[i + 2]; r3 += a[i + 3];
                    r4 += a[i + 4]; r5 += a[i + 5]; r6 += a[i + 6]; r7 += a[i + 7];
                }
                B[q] = ((r0 + r1) + (r2 + r3)) + ((r4 + r5) + (r6 + r7));
            }
            xx[blockIdx.x * 4 + wave] = (B[0] + B[1]) + (B[2] + B[3]);
        }
    }
}

// ---------------------------------------------------------------- kernel M
// fp16 MFMA candidate pass, operand-flipped (A=codes, B=x-rows), wave tile
// 64x64. BM=128 rows x BN=256 codes, BKH=64, 8 waves (2 row x 4 code groups).
// KSPLIT=2 -> grid 512 = 2 blocks/CU. Cs DOUBLE-BUFFERED with counted
// vmcnt(4): the 4 Cs loads for step+1 stay in flight across both barriers and
// the whole compute phase (T4); only the 2 Rs loads' latency is exposed.
// LDS = 16 (Rs) + 64 (Cs dbuf) = 80 KB = exactly 160/2 -> 2 blocks/CU kept.
#define BM 128
#define BN 256
#define BKH 64
#define KHALF 4096
#define NSTEP 128   // (KHALF/BN)=16 k0t * 8 kt

__global__ __launch_bounds__(512, 4) void vq_margmin(
    const ushortT* __restrict__ xh, const ushortT* __restrict__ eh,
    unsigned* __restrict__ gCode, unsigned* __restrict__ gCnt,
    int* __restrict__ fixcnt, int* __restrict__ fixlist) {
    __shared__ ushortT Rs[BM * BKH];      // 16 KB  x-rows tile (single buffer)
    __shared__ ushortT Cs[2][BN * BKH];   // 64 KB  codes tile (double buffer)
    // post-loop extras aliased into Rs (staging done by then):
    float* v1L        = (float*)&Rs[0];        // [128][4]  2 KB
    float* rowThr     = (float*)&Rs[1024];     // [128]     512 B
    unsigned* candCnt = (unsigned*)&Rs[1280];  // [128]     512 B
    int* flagL        = (int*)&Rs[1536];       // [128]     512 B
    unsigned* candList = (unsigned*)&Rs[1792]; // [128][16] u32 8 KB (ends 5888)

    const int t = threadIdx.x;
    const int l = t & 63;
    const int wid = t >> 6;
    const int wr = wid >> 2;      // 0..1 : 64-row region
    const int wc = wid & 3;       // 0..3 : 64-code region
    const int lr = l & 15;
    const int lg = l >> 4;
    const int rowBase = (blockIdx.x >> 1) * BM;
    const int kbase = (blockIdx.x & 1) * KHALF;

    // staging: rows 2 chunks/thread, codes 4 chunks/thread (16 B each)
    const ushortT* rSrc0; const ushortT* rSrc1;
    const ushortT* cSrc0; const ushortT* cSrc1; const ushortT* cSrc2; const ushortT* cSrc3;
    int rD0, rD1, cD0, cD1, cD2, cD3;
    {
        int f0 = t,        r0 = f0 >> 3, gs0 = (f0 & 7) ^ (r0 & 7);
        int f1 = t + 512,  r1 = f1 >> 3, gs1 = (f1 & 7) ^ (r1 & 7);
        int f2 = t + 1024, r2 = f2 >> 3, gs2 = (f2 & 7) ^ (r2 & 7);
        int f3 = t + 1536, r3 = f3 >> 3, gs3 = (f3 & 7) ^ (r3 & 7);
        rSrc0 = xh + (size_t)(rowBase + r0) * DIM + gs0 * 8;
        rSrc1 = xh + (size_t)(rowBase + r1) * DIM + gs1 * 8;
        rD0 = f0 * 8; rD1 = f1 * 8;
        cSrc0 = eh + (size_t)(kbase + r0) * DIM + gs0 * 8;
        cSrc1 = eh + (size_t)(kbase + r1) * DIM + gs1 * 8;
        cSrc2 = eh + (size_t)(kbase + r2) * DIM + gs2 * 8;
        cSrc3 = eh + (size_t)(kbase + r3) * DIM + gs3 * 8;
        cD0 = f0 * 8; cD1 = f1 * 8; cD2 = f2 * 8; cD3 = f3 * 8;
    }
    // frag base offsets (ushort units)
    int cB0 = (wc * 64 + 0 * 16 + lr) * 64, cB1 = (wc * 64 + 1 * 16 + lr) * 64;
    int cB2 = (wc * 64 + 2 * 16 + lr) * 64, cB3 = (wc * 64 + 3 * 16 + lr) * 64;
    int rB0 = (wr * 64 + 0 * 16 + lr) * 64, rB1 = (wr * 64 + 1 * 16 + lr) * 64;
    int rB2 = (wr * 64 + 2 * 16 + lr) * 64, rB3 = (wr * 64 + 3 * 16 + lr) * 64;

    float v1[4], v2m[4], v3m[4];
    int i1[4], i2[4];
#pragma unroll
    for (int nf = 0; nf < 4; ++nf) {
        v1[nf] = -FLT_BIG; v2m[nf] = -FLT_BIG; v3m[nf] = -FLT_BIG;
        i1[nf] = 0; i2[nf] = 0;
    }

    f32x4 acc[4][4];   // [mf codes][nf rows]

#define STAGE_C(stp, b) do {                                                   \
    int kt_ = ((stp) & 7) * BKH;                                               \
    size_t cAdd_ = (size_t)((stp) >> 3) * BN * DIM + kt_;                      \
    gload16(cSrc0 + cAdd_, &Cs[b][cD0]);                                       \
    gload16(cSrc1 + cAdd_, &Cs[b][cD1]);                                       \
    gload16(cSrc2 + cAdd_, &Cs[b][cD2]);                                       \
    gload16(cSrc3 + cAdd_, &Cs[b][cD3]);                                       \
} while (0)
#define STAGE_R(stp) do {                                                      \
    int kt_ = ((stp) & 7) * BKH;                                               \
    gload16(rSrc0 + kt_, &Rs[rD0]);                                            \
    gload16(rSrc1 + kt_, &Rs[rD1]);                                            \
} while (0)

    // prologue: Cs(0) + Rs(0) in flight
    STAGE_C(0, 0);
    STAGE_R(0);

    int cur = 0;
    for (int step = 0; step < NSTEP; ++step) {
        if ((step & 7) == 0) {
#pragma unroll
            for (int mf = 0; mf < 4; ++mf)
#pragma unroll
                for (int nf = 0; nf < 4; ++nf)
                    acc[mf][nf] = (f32x4){0.f, 0.f, 0.f, 0.f};
        }
        // issue next Cs tile into the buffer freed at the end of step-1;
        // counted wait: Rs(step)+Cs(step) retired, Cs(step+1) stays in flight.
        if (step + 1 < NSTEP) {
            STAGE_C(step + 1, cur ^ 1);
            asm volatile("s_waitcnt vmcnt(4)" ::: "memory");
        } else {
            asm volatile("s_waitcnt vmcnt(0)" ::: "memory");
        }
        __builtin_amdgcn_sched_barrier(0);
        __builtin_amdgcn_s_barrier();   // Rs(step), Cs(step) visible to all
#pragma unroll
        for (int kk = 0; kk < 2; ++kk) {
            const int sl = ((kk << 2) + lg) ^ (lr & 7);
            half8 a0 = *reinterpret_cast<const half8*>(&Cs[cur][cB0 + sl * 8]);
            half8 a1 = *reinterpret_cast<const half8*>(&Cs[cur][cB1 + sl * 8]);
            half8 a2 = *reinterpret_cast<const half8*>(&Cs[cur][cB2 + sl * 8]);
            half8 a3 = *reinterpret_cast<const half8*>(&Cs[cur][cB3 + sl * 8]);
            half8 b0 = *reinterpret_cast<const half8*>(&Rs[rB0 + sl * 8]);
            half8 b1 = *reinterpret_cast<const half8*>(&Rs[rB1 + sl * 8]);
            half8 b2 = *reinterpret_cast<const half8*>(&Rs[rB2 + sl * 8]);
            half8 b3 = *reinterpret_cast<const half8*>(&Rs[rB3 + sl * 8]);
            acc[0][0] = __builtin_amdgcn_mfma_f32_16x16x32_f16(a0, b0, acc[0][0], 0, 0, 0);
            acc[0][1] = __builtin_amdgcn_mfma_f32_16x16x32_f16(a0, b1, acc[0][1], 0, 0, 0);
            acc[0][2] = __builtin_amdgcn_mfma_f32_16x16x32_f16(a0, b2, acc[0][2], 0, 0, 0);
            acc[0][3] = __builtin_amdgcn_mfma_f32_16x16x32_f16(a0, b3, acc[0][3], 0, 0, 0);
            acc[1][0] = __builtin_amdgcn_mfma_f32_16x16x32_f16(a1, b0, acc[1][0], 0, 0, 0);
            acc[1][1] = __builtin_amdgcn_mfma_f32_16x16x32_f16(a1, b1, acc[1][1], 0, 0, 0);
            acc[1][2] = __builtin_amdgcn_mfma_f32_16x16x32_f16(a1, b2, acc[1][2], 0, 0, 0);
            acc[1][3] = __builtin_amdgcn_mfma_f32_16x16x32_f16(a1, b3, acc[1][3], 0, 0, 0);
            acc[2][0] = __builtin_amdgcn_mfma_f32_16x16x32_f16(a2, b0, acc[2][0], 0, 0, 0);
            acc[2][1] = __builtin_amdgcn_mfma_f32_16x16x32_f16(a2, b1, acc[2][1], 0, 0, 0);
            acc[2][2] = __builtin_amdgcn_mfma_f32_16x16x32_f16(a2, b2, acc[2][2], 0, 0, 0);
            acc[2][3] = __builtin_amdgcn_mfma_f32_16x16x32_f16(a2, b3, acc[2][3], 0, 0, 0);
            acc[3][0] = __builtin_amdgcn_mfma_f32_16x16x32_f16(a3, b0, acc[3][0], 0, 0, 0);
            acc[3][1] = __builtin_amdgcn_mfma_f32_16x16x32_f16(a3, b1, acc[3][1], 0, 0, 0);
            acc[3][2] = __builtin_amdgcn_mfma_f32_16x16x32_f16(a3, b2, acc[3][2], 0, 0, 0);
            acc[3][3] = __builtin_amdgcn_mfma_f32_16x16x32_f16(a3, b3, acc[3][3], 0, 0, 0);
        }
        if ((step & 7) == 7) {
            const int k0t = step >> 3;
#pragma unroll
            for (int nf = 0; nf < 4; ++nf) {
#pragma unroll
                for (int mf = 0; mf < 4; ++mf) {
                    const int tagB = (k0t << 4) | (mf << 2);
#pragma unroll
                    for (int rr = 0; rr < 4; ++rr) {
                        float s = acc[mf][nf][rr];
                        bool g1 = s > v1[nf];
                        bool g2 = s > v2m[nf];
                        bool g3 = s > v3m[nf];
                        v3m[nf] = g2 ? v2m[nf] : (g3 ? s : v3m[nf]);
                        i2[nf]  = g1 ? i1[nf]  : (g2 ? (tagB | rr) : i2[nf]);
                        v2m[nf] = g1 ? v1[nf]  : (g2 ? s : v2m[nf]);
                        i1[nf]  = g1 ? (tagB | rr) : i1[nf];
                        v1[nf]  = g1 ? s : v1[nf];
                    }
                }
            }
        }
        __builtin_amdgcn_s_barrier();   // all waves done reading Rs
        if (step + 1 < NSTEP) STAGE_R(step + 1);   // overwrite Rs (freed above)
        cur ^= 1;
    }
#undef STAGE_C
#undef STAGE_R

    __syncthreads();   // all compute done before aliasing Rs
    // ---- Phase A: in-wave row-max (4 lg lanes share an x-row: xor 16, 32)
#pragma unroll
    for (int nf = 0; nf < 4; ++nf) {
        float v = v1[nf];
        v = fmaxf(v, __shfl_xor(v, 16));
        v = fmaxf(v, __shfl_xor(v, 32));
        if (l < 16) v1L[(wr * 64 + nf * 16 + l) * 4 + wc] = v;
    }
    __syncthreads();
    // ---- Phase B: per-row local threshold + init
    if (t < BM) {
        float m = fmaxf(fmaxf(v1L[t * 4], v1L[t * 4 + 1]),
                        fmaxf(v1L[t * 4 + 2], v1L[t * 4 + 3]));
        rowThr[t] = m - W_ACC;
        candCnt[t] = 0u;
        flagL[t] = 0;
    }
    __syncthreads();
    // ---- Phase C: candidate pushes (packed score|code) + 3rd-value flag
#pragma unroll
    for (int nf = 0; nf < 4; ++nf) {
        const int row = wr * 64 + nf * 16 + lr;
        const float thr = rowThr[row];
        if (v1[nf] >= thr) {
            unsigned pos = atomicAdd(&candCnt[row], 1u);
            int tg = i1[nf];
            int code = kbase + ((tg >> 4) << 8) + wc * 64 + (((tg >> 2) & 3) << 4) + lg * 4 + (tg & 3);
            unsigned pk = ((unsigned)__half_as_ushort(__float2half(v1[nf])) << 16) | (unsigned)code;
            if (pos < GCAP) candList[row * GCAP + pos] = pk;
            else flagL[row] = 1;
        }
        if (v2m[nf] >= thr) {
            unsigned pos = atomicAdd(&candCnt[row], 1u);
            int tg = i2[nf];
            int code = kbase + ((tg >> 4) << 8) + wc * 64 + (((tg >> 2) & 3) << 4) + lg * 4 + (tg & 3);
            unsigned pk = ((unsigned)__half_as_ushort(__float2half(v2m[nf])) << 16) | (unsigned)code;
            if (pos < GCAP) candList[row * GCAP + pos] = pk;
            else flagL[row] = 1;
        }
        if (v3m[nf] >= thr) flagL[row] = 1;
    }
    __syncthreads();
    // ---- Phase D: merge into global candidate list via atomics
    if (t < BM) {
        const int grow = rowBase + t;
        unsigned cc = candCnt[t];
        bool ovf = (flagL[t] != 0) || (cc > GCAP);
        if (!ovf) {
            for (unsigned j = 0; j < cc; ++j) {
                unsigned pos = atomicAdd(&gCnt[grow], 1u);
                if (pos < GCAP) gCode[(size_t)grow * GCAP + pos] = candList[t * GCAP + j];
                else ovf = true;
            }
        }
        if (ovf) {
            int p = atomicAdd(fixcnt, 1);
            fixlist[p] = grow;
        }
    }
}

// ---------------------------------------------------------------- refine
// Filter candidates by packed fp16 score vs global max, then fp64-exact dots
// with quantized compare s=fl32(xx-(f32)(2*dot)), first-index tie-break.
__global__ __launch_bounds__(256) void vq_refine(
    const float* __restrict__ x, const float* __restrict__ cb,
    const float* __restrict__ xx, const unsigned* __restrict__ gCode,
    const unsigned* __restrict__ gCnt, float* __restrict__ outIdxF,
    int* __restrict__ idxI) {
    const int wave = threadIdx.x >> 6;
    const int lane = threadIdx.x & 63;
    const int row = blockIdx.x * 4 + wave;
    const unsigned cc = gCnt[row];
    if (cc == 0u || cc > GCAP) return;   // fixup overrides these rows later
    float gmax = -FLT_BIG;
    for (unsigned c = 0; c < cc; ++c) {
        unsigned e = gCode[(size_t)row * GCAP + c];
        gmax = fmaxf(gmax, __half2float(__ushort_as_half((ushortT)(e >> 16))));
    }
    const float fthr = gmax - W_FILT;
    const float* xr = x + (size_t)row * DIM;
    float4 xa = *reinterpret_cast<const float4*>(xr + lane * 8);
    float4 xb = *reinterpret_cast<const float4*>(xr + lane * 8 + 4);
    const float xxrow = xx[row];
    float best = FLT_BIG;
    int bi = 0x7fffffff;
    for (unsigned c = 0; c < cc; ++c) {
        unsigned e = gCode[(size_t)row * GCAP + c];
        if (__half2float(__ushort_as_half((ushortT)(e >> 16))) < fthr) continue;
        int code = (int)(e & 0xFFFFu);
        const float* er = cb + (size_t)code * DIM;
        float4 ea = *reinterpret_cast<const float4*>(er + lane * 8);
        float4 eb = *reinterpret_cast<const float4*>(er + lane * 8 + 4);
        double p = (double)xa.x * ea.x + (double)xa.y * ea.y
                 + (double)xa.z * ea.z + (double)xa.w * ea.w
                 + (double)xb.x * eb.x + (double)xb.y * eb.y
                 + (double)xb.z * eb.z + (double)xb.w * eb.w;
#pragma unroll
        for (int off = 1; off < 64; off <<= 1) p += __shfl_xor(p, off);
        float sc = xxrow - (float)(2.0 * p);
        if (sc < best || (sc == best && code < bi)) { best = sc; bi = code; }
    }
    if (lane == 0) { idxI[row] = bi; outIdxF[row] = (float)bi; }
}

// ---------------------------------------------------------------- fixup A
// Parallel exact re-rank of flagged rows (wave per 64-code chunk).
__global__ __launch_bounds__(256) void vq_fixup_scan(
    const float* __restrict__ x, const float* __restrict__ cb,
    const float* __restrict__ xx, const int* __restrict__ cnt,
    const int* __restrict__ list, unsigned long long* __restrict__ fixmin) {
    const int nflag = *cnt;
    if (nflag == 0) return;
    const int gw = (blockIdx.x * 256 + threadIdx.x) >> 6;
    const int lane = threadIdx.x & 63;
    const int nwaves = gridDim.x * 4;
    const int totalUnits = nflag * 128;
    for (int u = gw; u < totalUnits; u += nwaves) {
        const int row = list[u >> 7];
        const int kb = (u & 127) * 64;
        const float* xr = x + (size_t)row * DIM;
        float4 xa = *reinterpret_cast<const float4*>(xr + lane * 8);
        float4 xb = *reinterpret_cast<const float4*>(xr + lane * 8 + 4);
        const float xxrow = xx[row];
        unsigned long long best = ~0ULL;
        for (int k = kb; k < kb + 64; ++k) {
            const float* er = cb + (size_t)k * DIM;
            float4 ea = *reinterpret_cast<const float4*>(er + lane * 8);
            float4 eb = *reinterpret_cast<const float4*>(er + lane * 8 + 4);
            double p = (double)xa.x * ea.x + (double)xa.y * ea.y
                     + (double)xa.z * ea.z + (double)xa.w * ea.w
                     + (double)xb.x * eb.x + (double)xb.y * eb.y
                     + (double)xb.z * eb.z + (double)xb.w * eb.w;
#pragma unroll
            for (int off = 1; off < 64; off <<= 1) p += __shfl_xor(p, off);
            float sc = xxrow - (float)(2.0 * p);
            unsigned long long key =
                ((unsigned long long)__float_as_uint(sc) << 32) | (unsigned)k;
            best = (key < best) ? key : best;
        }
        if (lane == 0) atomicMin(&fixmin[row], best);
    }
}

// ---------------------------------------------------------------- fixup B
__global__ __launch_bounds__(256) void vq_fixup_write(
    const int* __restrict__ cnt, const int* __restrict__ list,
    const unsigned long long* __restrict__ fixmin,
    float* __restrict__ outIdxF, int* __restrict__ idxI) {
    const int i = blockIdx.x * 256 + threadIdx.x;
    if (i >= *cnt) return;
    const int row = list[i];
    const int code = (int)(unsigned)(fixmin[row] & 0xFFFFFFFFULL);
    idxI[row] = code;
    outIdxF[row] = (float)code;
}

// ---------------------------------------------------------------- gather
__global__ __launch_bounds__(256) void vq_gather_kernel(
    const float* __restrict__ x, const float* __restrict__ cb,
    const int* __restrict__ idxI, float* __restrict__ outQ,
    float* __restrict__ partial) {
    const int wave = threadIdx.x >> 6;
    const int lane = threadIdx.x & 63;
    const int row = blockIdx.x * 4 + wave;
    const int code = idxI[row];
    const float* xr = x + (size_t)row * DIM;
    const float* er = cb + (size_t)code * DIM;
    float* qr = outQ + (size_t)row * DIM;
    float s = 0.f;
#pragma unroll
    for (int i = 0; i < 2; ++i) {
        int d = lane * 8 + i * 4;
        float4 xv = *reinterpret_cast<const float4*>(xr + d);
        float4 ev = *reinterpret_cast<const float4*>(er + d);
        float4 dv = make_float4(ev.x - xv.x, ev.y - xv.y, ev.z - xv.z, ev.w - xv.w);
        *reinterpret_cast<float4*>(qr + d) = ev;
        s += dv.x * dv.x + dv.y * dv.y + dv.z * dv.z + dv.w * dv.w;
    }
#pragma unroll
    for (int off = 32; off > 0; off >>= 1) s += __shfl_xor(s, off);
    __shared__ float ws4[4];
    if (lane == 0) ws4[wave] = s;
    __syncthreads();
    if (threadIdx.x == 0)
        partial[blockIdx.x] = (ws4[0] + ws4[1]) + (ws4[2] + ws4[3]);
}

// ---------------------------------------------------------------- loss
__global__ __launch_bounds__(256) void vq_loss_kernel(const float* __restrict__ partial,
                                                      float* __restrict__ outLoss) {
    float s = 0.f;
    for (int i = threadIdx.x; i < 8192; i += 256) s += partial[i];
    __shared__ float sm[256];
    sm[threadIdx.x] = s;
    __syncthreads();
    for (int off = 128; off > 0; off >>= 1) {
        if (threadIdx.x < off) sm[threadIdx.x] += sm[threadIdx.x + off];
        __syncthreads();
    }
    if (threadIdx.x == 0)
        outLoss[0] = sm[0] * (1.0f + BETA) / 16777216.0f;
}

// ---------------------------------------------------------------- launch
extern "C" void kernel_launch(void* const* d_in, const int* in_sizes, int n_in,
                              void* d_out, int out_size, void* d_ws, size_t ws_size,
                              hipStream_t stream) {
    const float* x = (const float*)d_in[0];   // [32768, 512]
    const float* cb = (const float*)d_in[1];  // [8192, 512]
    float* out = (float*)d_out;

    // d_out scratch (rewritten by gather at the end)
    ushortT* xh = (ushortT*)out;
    ushortT* eh = (ushortT*)(out + SC_EH_F);
    unsigned* gCode = (unsigned*)(out + SC_GCODE_F);
    unsigned* gCnt = (unsigned*)(out + SC_GCNT_F);
    unsigned long long* fixmin = (unsigned long long*)(out + SC_FIXMIN_F);
    int* fixlist = (int*)(out + SC_FIXLIST_F);

    float* xx = (float*)d_ws + WS_XX_OFF;
    int* idxI = (int*)d_ws + WS_IDX_OFF;
    float* partial = (float*)d_ws + WS_PART_OFF;
    int* fixcnt = (int*)d_ws + WS_CNT_OFF;

    hipLaunchKernelGGL(vq_init, dim3(128), dim3(256), 0, stream, gCnt, fixmin, fixcnt);
    hipLaunchKernelGGL(vq_prep, dim3(10240), dim3(256), 0, stream, x, cb, xh, eh, xx);
    hipLaunchKernelGGL(vq_margmin, dim3((N_ROWS / BM) * 2), dim3(512), 0, stream,
                       xh, eh, gCode, gCnt, fixcnt, fixlist);
    hipLaunchKernelGGL(vq_refine, dim3(N_ROWS / 4), dim3(256), 0, stream,
                       x, cb, xx, gCode, gCnt, out + IDX_OFF, idxI);
    hipLaunchKernelGGL(vq_fixup_scan, dim3(2048), dim3(256), 0, stream,
                       x, cb, xx, fixcnt, fixlist, fixmin);
    hipLaunchKernelGGL(vq_fixup_write, dim3(256), dim3(256), 0, stream,
                       fixcnt, fixlist, fixmin, out + IDX_OFF, idxI);
    hipLaunchKernelGGL(vq_gather_kernel, dim3(N_ROWS / 4), dim3(256), 0, stream,
                       x, cb, idxI, out, partial);
    hipLaunchKernelGGL(vq_loss_kernel, dim3(1), dim3(256), 0, stream,
                       partial, out + LOSS_OFF);
}

// Round 15
// 465.612 us; speedup vs baseline: 1.1921x; 1.1921x over previous
//
#include <hip/hip_runtime.h>
#include <hip/hip_bf16.h>
#include <hip/hip_fp16.h>

typedef unsigned short ushortT;
typedef _Float16 half8 __attribute__((ext_vector_type(8)));
typedef float f32x4 __attribute__((ext_vector_type(4)));

#define N_ROWS   32768
#define DIM      512
#define K_CODES  8192
#define BETA     0.01f

// d_out layout (floats): [quantized 16777216][loss 1][indices-as-float 32768]
#define LOSS_OFF 16777216
#define IDX_OFF  16777217

// d_out-as-scratch (float offsets). Audited map (all disjoint):
//   xh      [0,        8388608)   32768*512 halves
//   eh      [8388608,  10485760)  8192*512 halves
//   gCode   [10485760, 11010048)  32768*16 u32 (packed score<<16|code)
//   gCnt    [11010048, 11042816)  32768 u32
//   fixmin  [11042816, 11108352)  32768 u64 (8B-aligned)
//   fixlist [11108352, 11173888)  65536 i32 (KSPLIT=2: <=2 entries/row)
// ORDERING RULE (round-14 lesson): everything reading this scratch must
// complete BEFORE vq_gather launches — gather overwrites [0, 16.7M).
#define SC_XH_F      0
#define SC_EH_F      8388608
#define SC_GCODE_F   10485760
#define SC_GCNT_F    11010048
#define SC_FIXMIN_F  11042816
#define SC_FIXLIST_F 11108352

// d_ws layout (4-byte units): xx[32768] | idx[32768] | partial[8192] | cnt[1]
#define WS_XX_OFF     0
#define WS_IDX_OFF    32768
#define WS_PART_OFF   65536
#define WS_CNT_OFF    73728

#define FLT_BIG 3.402823466e+38f
#define W_ACC   0.08192f   // 1.6e-4 (s-domain window) * 512 (acc scale = 1024/2)
#define W_FILT  0.09192f   // W_ACC + fp16-packing slack
#define GCAP    16

typedef __attribute__((address_space(1))) const unsigned int GUI;
typedef __attribute__((address_space(3))) unsigned int LUI;
__device__ __forceinline__ void gload16(const void* g, void* l) {
    __builtin_amdgcn_global_load_lds((GUI*)g, (LUI*)l, 16, 0, 0);
}

// ---------------------------------------------------------------- init
// One dispatch replacing 3 hipMemsetAsync: gCnt=0, fixmin=~0, fixcnt=0.
__global__ __launch_bounds__(256) void vq_init(unsigned* __restrict__ gCnt,
                                               unsigned long long* __restrict__ fixmin,
                                               int* __restrict__ fixcnt) {
    const int i = blockIdx.x * 256 + threadIdx.x;   // grid 128 -> 32768 threads
    gCnt[i] = 0u;
    fixmin[i] = ~0ULL;
    if (i == 0) *fixcnt = 0;
}

// ---------------------------------------------------------------- prep (+xx fused)
// xh = fp16(x); eh = fp16(1024*e). Blocks < 8192 also compute xx[row] with the
// numpy-pairwise-exact tree (proven round 3) from the already-loaded x values.
__global__ __launch_bounds__(256) void vq_prep(const float* __restrict__ x,
                                               const float* __restrict__ cb,
                                               ushortT* __restrict__ xh,
                                               ushortT* __restrict__ eh,
                                               float* __restrict__ xx) {
    __shared__ float l[4][512];
    const size_t gid = (size_t)blockIdx.x * 256 + threadIdx.x;
    const size_t off8 = gid * 8;
    const bool isX = (blockIdx.x < 8192);
    const float* src;
    ushortT* dst;
    float sc;
    if (isX) { src = x + off8; dst = xh + off8; sc = 1.0f; }
    else { size_t o = off8 - 16777216UL; src = cb + o; dst = eh + o; sc = 1024.0f; }
    float4 v0 = *reinterpret_cast<const float4*>(src);
    float4 v1 = *reinterpret_cast<const float4*>(src + 4);
    union { ushortT s[8]; uint4 v; } u;
    u.s[0] = __half_as_ushort(__float2half(v0.x * sc));
    u.s[1] = __half_as_ushort(__float2half(v0.y * sc));
    u.s[2] = __half_as_ushort(__float2half(v0.z * sc));
    u.s[3] = __half_as_ushort(__float2half(v0.w * sc));
    u.s[4] = __half_as_ushort(__float2half(v1.x * sc));
    u.s[5] = __half_as_ushort(__float2half(v1.y * sc));
    u.s[6] = __half_as_ushort(__float2half(v1.z * sc));
    u.s[7] = __half_as_ushort(__float2half(v1.w * sc));
    *reinterpret_cast<uint4*>(dst) = u.v;
    if (isX) {
        const int wave = threadIdx.x >> 6;
        const int lane = threadIdx.x & 63;
        float4 q0 = make_float4(v0.x * v0.x, v0.y * v0.y, v0.z * v0.z, v0.w * v0.w);
        float4 q1 = make_float4(v1.x * v1.x, v1.y * v1.y, v1.z * v1.z, v1.w * v1.w);
        *reinterpret_cast<float4*>(&l[wave][lane * 8]) = q0;
        *reinterpret_cast<float4*>(&l[wave][lane * 8 + 4]) = q1;
        __syncthreads();
        if (lane == 0) {
            float B[4];
#pragma unroll
            for (int q = 0; q < 4; ++q) {
                const float* a = &l[wave][q * 128];
                float r0 = a[0], r1 = a[1], r2 = a[2], r3 = a[3];
                float r4 = a[4], r5 = a[5], r6 = a[6], r7 = a[7];
                for (int i = 8; i < 128; i += 8) {
                    r0 += a[i + 0]; r1 += a[i + 1]; r2 += a[i + 2]; r3 += a[i + 3];
                    r4 += a[i + 4]; r5 += a[i + 5]; r6 += a[i + 6]; r7 += a[i + 7];
                }
                B[q] = ((r0 + r1) + (r2 + r3)) + ((r4 + r5) + (r6 + r7));
            }
            xx[blockIdx.x * 4 + wave] = (B[0] + B[1]) + (B[2] + B[3]);
        }
    }
}

// ---------------------------------------------------------------- kernel M
// fp16 MFMA candidate pass, operand-flipped (A=codes, B=x-rows), wave tile
// 64x64. BM=128 rows x BN=256 codes, BKH=64, 8 waves (2 row x 4 code groups).
// KSPLIT=2 -> grid 512 = 2 blocks/CU; 48 KB single-buffer LDS, 2-barrier loop.
// [round-12 proven version: 330 us, MfmaUtil 38%, no spill. r13's Cs-dbuf
// spilled registers under the 128-VGPR cap; r7's depth-2 pipeline was neutral
// — the co-resident block already hides most of the staging latency.]
#define BM 128
#define BN 256
#define BKH 64
#define KHALF 4096
#define NSTEP 128   // (KHALF/BN)=16 k0t * 8 kt

__global__ __launch_bounds__(512, 4) void vq_margmin(
    const ushortT* __restrict__ xh, const ushortT* __restrict__ eh,
    unsigned* __restrict__ gCode, unsigned* __restrict__ gCnt,
    int* __restrict__ fixcnt, int* __restrict__ fixlist) {
    __shared__ ushortT Rs[BM * BKH];   // 16 KB  x-rows tile
    __shared__ ushortT Cs[BN * BKH];   // 32 KB  codes tile
    // post-loop extras aliased into Rs (staging done by then):
    float* v1L        = (float*)&Rs[0];        // [128][4]  2 KB
    float* rowThr     = (float*)&Rs[1024];     // [128]     512 B
    unsigned* candCnt = (unsigned*)&Rs[1280];  // [128]     512 B
    int* flagL        = (int*)&Rs[1536];       // [128]     512 B
    unsigned* candList = (unsigned*)&Rs[1792]; // [128][16] u32 8 KB (ends 5888)

    const int t = threadIdx.x;
    const int l = t & 63;
    const int wid = t >> 6;
    const int wr = wid >> 2;      // 0..1 : 64-row region
    const int wc = wid & 3;       // 0..3 : 64-code region
    const int lr = l & 15;
    const int lg = l >> 4;
    const int rowBase = (blockIdx.x >> 1) * BM;
    const int kbase = (blockIdx.x & 1) * KHALF;

    // staging: rows 2 chunks/thread, codes 4 chunks/thread (16 B each)
    const ushortT* rSrc0; const ushortT* rSrc1;
    const ushortT* cSrc0; const ushortT* cSrc1; const ushortT* cSrc2; const ushortT* cSrc3;
    int rD0, rD1, cD0, cD1, cD2, cD3;
    {
        int f0 = t,        r0 = f0 >> 3, gs0 = (f0 & 7) ^ (r0 & 7);
        int f1 = t + 512,  r1 = f1 >> 3, gs1 = (f1 & 7) ^ (r1 & 7);
        int f2 = t + 1024, r2 = f2 >> 3, gs2 = (f2 & 7) ^ (r2 & 7);
        int f3 = t + 1536, r3 = f3 >> 3, gs3 = (f3 & 7) ^ (r3 & 7);
        rSrc0 = xh + (size_t)(rowBase + r0) * DIM + gs0 * 8;
        rSrc1 = xh + (size_t)(rowBase + r1) * DIM + gs1 * 8;
        rD0 = f0 * 8; rD1 = f1 * 8;
        cSrc0 = eh + (size_t)(kbase + r0) * DIM + gs0 * 8;
        cSrc1 = eh + (size_t)(kbase + r1) * DIM + gs1 * 8;
        cSrc2 = eh + (size_t)(kbase + r2) * DIM + gs2 * 8;
        cSrc3 = eh + (size_t)(kbase + r3) * DIM + gs3 * 8;
        cD0 = f0 * 8; cD1 = f1 * 8; cD2 = f2 * 8; cD3 = f3 * 8;
    }
    // frag base offsets (ushort units)
    int cB0 = (wc * 64 + 0 * 16 + lr) * 64, cB1 = (wc * 64 + 1 * 16 + lr) * 64;
    int cB2 = (wc * 64 + 2 * 16 + lr) * 64, cB3 = (wc * 64 + 3 * 16 + lr) * 64;
    int rB0 = (wr * 64 + 0 * 16 + lr) * 64, rB1 = (wr * 64 + 1 * 16 + lr) * 64;
    int rB2 = (wr * 64 + 2 * 16 + lr) * 64, rB3 = (wr * 64 + 3 * 16 + lr) * 64;

    float v1[4], v2m[4], v3m[4];
    int i1[4], i2[4];
#pragma unroll
    for (int nf = 0; nf < 4; ++nf) {
        v1[nf] = -FLT_BIG; v2m[nf] = -FLT_BIG; v3m[nf] = -FLT_BIG;
        i1[nf] = 0; i2[nf] = 0;
    }

    f32x4 acc[4][4];   // [mf codes][nf rows]

#define STAGE(stp) do {                                                        \
    int kt_ = ((stp) & 7) * BKH;                                               \
    size_t cAdd_ = (size_t)((stp) >> 3) * BN * DIM + kt_;                      \
    gload16(rSrc0 + kt_, &Rs[rD0]);                                            \
    gload16(rSrc1 + kt_, &Rs[rD1]);                                            \
    gload16(cSrc0 + cAdd_, &Cs[cD0]);                                          \
    gload16(cSrc1 + cAdd_, &Cs[cD1]);                                          \
    gload16(cSrc2 + cAdd_, &Cs[cD2]);                                          \
    gload16(cSrc3 + cAdd_, &Cs[cD3]);                                          \
} while (0)

    for (int step = 0; step < NSTEP; ++step) {
        if ((step & 7) == 0) {
#pragma unroll
            for (int mf = 0; mf < 4; ++mf)
#pragma unroll
                for (int nf = 0; nf < 4; ++nf)
                    acc[mf][nf] = (f32x4){0.f, 0.f, 0.f, 0.f};
        }
        __syncthreads();           // all waves done reading previous tile
        STAGE(step);
        __syncthreads();           // drains vmcnt(0); tile visible
#pragma unroll
        for (int kk = 0; kk < 2; ++kk) {
            const int sl = ((kk << 2) + lg) ^ (lr & 7);
            half8 a0 = *reinterpret_cast<const half8*>(&Cs[cB0 + sl * 8]);
            half8 a1 = *reinterpret_cast<const half8*>(&Cs[cB1 + sl * 8]);
            half8 a2 = *reinterpret_cast<const half8*>(&Cs[cB2 + sl * 8]);
            half8 a3 = *reinterpret_cast<const half8*>(&Cs[cB3 + sl * 8]);
            half8 b0 = *reinterpret_cast<const half8*>(&Rs[rB0 + sl * 8]);
            half8 b1 = *reinterpret_cast<const half8*>(&Rs[rB1 + sl * 8]);
            half8 b2 = *reinterpret_cast<const half8*>(&Rs[rB2 + sl * 8]);
            half8 b3 = *reinterpret_cast<const half8*>(&Rs[rB3 + sl * 8]);
            acc[0][0] = __builtin_amdgcn_mfma_f32_16x16x32_f16(a0, b0, acc[0][0], 0, 0, 0);
            acc[0][1] = __builtin_amdgcn_mfma_f32_16x16x32_f16(a0, b1, acc[0][1], 0, 0, 0);
            acc[0][2] = __builtin_amdgcn_mfma_f32_16x16x32_f16(a0, b2, acc[0][2], 0, 0, 0);
            acc[0][3] = __builtin_amdgcn_mfma_f32_16x16x32_f16(a0, b3, acc[0][3], 0, 0, 0);
            acc[1][0] = __builtin_amdgcn_mfma_f32_16x16x32_f16(a1, b0, acc[1][0], 0, 0, 0);
            acc[1][1] = __builtin_amdgcn_mfma_f32_16x16x32_f16(a1, b1, acc[1][1], 0, 0, 0);
            acc[1][2] = __builtin_amdgcn_mfma_f32_16x16x32_f16(a1, b2, acc[1][2], 0, 0, 0);
            acc[1][3] = __builtin_amdgcn_mfma_f32_16x16x32_f16(a1, b3, acc[1][3], 0, 0, 0);
            acc[2][0] = __builtin_amdgcn_mfma_f32_16x16x32_f16(a2, b0, acc[2][0], 0, 0, 0);
            acc[2][1] = __builtin_amdgcn_mfma_f32_16x16x32_f16(a2, b1, acc[2][1], 0, 0, 0);
            acc[2][2] = __builtin_amdgcn_mfma_f32_16x16x32_f16(a2, b2, acc[2][2], 0, 0, 0);
            acc[2][3] = __builtin_amdgcn_mfma_f32_16x16x32_f16(a2, b3, acc[2][3], 0, 0, 0);
            acc[3][0] = __builtin_amdgcn_mfma_f32_16x16x32_f16(a3, b0, acc[3][0], 0, 0, 0);
            acc[3][1] = __builtin_amdgcn_mfma_f32_16x16x32_f16(a3, b1, acc[3][1], 0, 0, 0);
            acc[3][2] = __builtin_amdgcn_mfma_f32_16x16x32_f16(a3, b2, acc[3][2], 0, 0, 0);
            acc[3][3] = __builtin_amdgcn_mfma_f32_16x16x32_f16(a3, b3, acc[3][3], 0, 0, 0);
        }
        if ((step & 7) == 7) {
            const int k0t = step >> 3;
#pragma unroll
            for (int nf = 0; nf < 4; ++nf) {
#pragma unroll
                for (int mf = 0; mf < 4; ++mf) {
                    const int tagB = (k0t << 4) | (mf << 2);
#pragma unroll
                    for (int rr = 0; rr < 4; ++rr) {
                        float s = acc[mf][nf][rr];
                        bool g1 = s > v1[nf];
                        bool g2 = s > v2m[nf];
                        bool g3 = s > v3m[nf];
                        v3m[nf] = g2 ? v2m[nf] : (g3 ? s : v3m[nf]);
                        i2[nf]  = g1 ? i1[nf]  : (g2 ? (tagB | rr) : i2[nf]);
                        v2m[nf] = g1 ? v1[nf]  : (g2 ? s : v2m[nf]);
                        i1[nf]  = g1 ? (tagB | rr) : i1[nf];
                        v1[nf]  = g1 ? s : v1[nf];
                    }
                }
            }
        }
    }
#undef STAGE

    __syncthreads();   // all compute done before aliasing Rs
    // ---- Phase A: in-wave row-max (4 lg lanes share an x-row: xor 16, 32)
#pragma unroll
    for (int nf = 0; nf < 4; ++nf) {
        float v = v1[nf];
        v = fmaxf(v, __shfl_xor(v, 16));
        v = fmaxf(v, __shfl_xor(v, 32));
        if (l < 16) v1L[(wr * 64 + nf * 16 + l) * 4 + wc] = v;
    }
    __syncthreads();
    // ---- Phase B: per-row local threshold + init
    if (t < BM) {
        float m = fmaxf(fmaxf(v1L[t * 4], v1L[t * 4 + 1]),
                        fmaxf(v1L[t * 4 + 2], v1L[t * 4 + 3]));
        rowThr[t] = m - W_ACC;
        candCnt[t] = 0u;
        flagL[t] = 0;
    }
    __syncthreads();
    // ---- Phase C: candidate pushes (packed score|code) + 3rd-value flag
#pragma unroll
    for (int nf = 0; nf < 4; ++nf) {
        const int row = wr * 64 + nf * 16 + lr;
        const float thr = rowThr[row];
        if (v1[nf] >= thr) {
            unsigned pos = atomicAdd(&candCnt[row], 1u);
            int tg = i1[nf];
            int code = kbase + ((tg >> 4) << 8) + wc * 64 + (((tg >> 2) & 3) << 4) + lg * 4 + (tg & 3);
            unsigned pk = ((unsigned)__half_as_ushort(__float2half(v1[nf])) << 16) | (unsigned)code;
            if (pos < GCAP) candList[row * GCAP + pos] = pk;
            else flagL[row] = 1;
        }
        if (v2m[nf] >= thr) {
            unsigned pos = atomicAdd(&candCnt[row], 1u);
            int tg = i2[nf];
            int code = kbase + ((tg >> 4) << 8) + wc * 64 + (((tg >> 2) & 3) << 4) + lg * 4 + (tg & 3);
            unsigned pk = ((unsigned)__half_as_ushort(__float2half(v2m[nf])) << 16) | (unsigned)code;
            if (pos < GCAP) candList[row * GCAP + pos] = pk;
            else flagL[row] = 1;
        }
        if (v3m[nf] >= thr) flagL[row] = 1;
    }
    __syncthreads();
    // ---- Phase D: merge into global candidate list via atomics
    if (t < BM) {
        const int grow = rowBase + t;
        unsigned cc = candCnt[t];
        bool ovf = (flagL[t] != 0) || (cc > GCAP);
        if (!ovf) {
            for (unsigned j = 0; j < cc; ++j) {
                unsigned pos = atomicAdd(&gCnt[grow], 1u);
                if (pos < GCAP) gCode[(size_t)grow * GCAP + pos] = candList[t * GCAP + j];
                else ovf = true;
            }
        }
        if (ovf) {
            int p = atomicAdd(fixcnt, 1);
            fixlist[p] = grow;
        }
    }
}

// ---------------------------------------------------------------- refine
// Filter candidates by packed fp16 score vs global max, then fp64-exact dots
// with quantized compare s=fl32(xx-(f32)(2*dot)), first-index tie-break.
__global__ __launch_bounds__(256) void vq_refine(
    const float* __restrict__ x, const float* __restrict__ cb,
    const float* __restrict__ xx, const unsigned* __restrict__ gCode,
    const unsigned* __restrict__ gCnt, float* __restrict__ outIdxF,
    int* __restrict__ idxI) {
    const int wave = threadIdx.x >> 6;
    const int lane = threadIdx.x & 63;
    const int row = blockIdx.x * 4 + wave;
    const unsigned cc = gCnt[row];
    if (cc == 0u || cc > GCAP) return;   // fixup_write overrides these rows
    float gmax = -FLT_BIG;
    for (unsigned c = 0; c < cc; ++c) {
        unsigned e = gCode[(size_t)row * GCAP + c];
        gmax = fmaxf(gmax, __half2float(__ushort_as_half((ushortT)(e >> 16))));
    }
    const float fthr = gmax - W_FILT;
    const float* xr = x + (size_t)row * DIM;
    float4 xa = *reinterpret_cast<const float4*>(xr + lane * 8);
    float4 xb = *reinterpret_cast<const float4*>(xr + lane * 8 + 4);
    const float xxrow = xx[row];
    float best = FLT_BIG;
    int bi = 0x7fffffff;
    for (unsigned c = 0; c < cc; ++c) {
        unsigned e = gCode[(size_t)row * GCAP + c];
        if (__half2float(__ushort_as_half((ushortT)(e >> 16))) < fthr) continue;
        int code = (int)(e & 0xFFFFu);
        const float* er = cb + (size_t)code * DIM;
        float4 ea = *reinterpret_cast<const float4*>(er + lane * 8);
        float4 eb = *reinterpret_cast<const float4*>(er + lane * 8 + 4);
        double p = (double)xa.x * ea.x + (double)xa.y * ea.y
                 + (double)xa.z * ea.z + (double)xa.w * ea.w
                 + (double)xb.x * eb.x + (double)xb.y * eb.y
                 + (double)xb.z * eb.z + (double)xb.w * eb.w;
#pragma unroll
        for (int off = 1; off < 64; off <<= 1) p += __shfl_xor(p, off);
        float sc = xxrow - (float)(2.0 * p);
        if (sc < best || (sc == best && code < bi)) { best = sc; bi = code; }
    }
    if (lane == 0) { idxI[row] = bi; outIdxF[row] = (float)bi; }
}

// ---------------------------------------------------------------- fixup A
// Parallel exact re-rank of flagged rows (wave per 64-code chunk).
__global__ __launch_bounds__(256) void vq_fixup_scan(
    const float* __restrict__ x, const float* __restrict__ cb,
    const float* __restrict__ xx, const int* __restrict__ cnt,
    const int* __restrict__ list, unsigned long long* __restrict__ fixmin) {
    const int nflag = *cnt;
    if (nflag == 0) return;
    const int gw = (blockIdx.x * 256 + threadIdx.x) >> 6;
    const int lane = threadIdx.x & 63;
    const int nwaves = gridDim.x * 4;
    const int totalUnits = nflag * 128;
    for (int u = gw; u < totalUnits; u += nwaves) {
        const int row = list[u >> 7];
        const int kb = (u & 127) * 64;
        const float* xr = x + (size_t)row * DIM;
        float4 xa = *reinterpret_cast<const float4*>(xr + lane * 8);
        float4 xb = *reinterpret_cast<const float4*>(xr + lane * 8 + 4);
        const float xxrow = xx[row];
        unsigned long long best = ~0ULL;
        for (int k = kb; k < kb + 64; ++k) {
            const float* er = cb + (size_t)k * DIM;
            float4 ea = *reinterpret_cast<const float4*>(er + lane * 8);
            float4 eb = *reinterpret_cast<const float4*>(er + lane * 8 + 4);
            double p = (double)xa.x * ea.x + (double)xa.y * ea.y
                     + (double)xa.z * ea.z + (double)xa.w * ea.w
                     + (double)xb.x * eb.x + (double)xb.y * eb.y
                     + (double)xb.z * eb.z + (double)xb.w * eb.w;
#pragma unroll
            for (int off = 1; off < 64; off <<= 1) p += __shfl_xor(p, off);
            float sc = xxrow - (float)(2.0 * p);
            unsigned long long key =
                ((unsigned long long)__float_as_uint(sc) << 32) | (unsigned)k;
            best = (key < best) ? key : best;
        }
        if (lane == 0) atomicMin(&fixmin[row], best);
    }
}

// ---------------------------------------------------------------- fixup B
// Consumes fixmin BEFORE gather (gather overwrites the scratch region).
__global__ __launch_bounds__(256) void vq_fixup_write(
    const int* __restrict__ cnt, const int* __restrict__ list,
    const unsigned long long* __restrict__ fixmin,
    float* __restrict__ outIdxF, int* __restrict__ idxI) {
    const int i = blockIdx.x * 256 + threadIdx.x;
    if (i >= *cnt) return;
    const int row = list[i];
    const int code = (int)(unsigned)(fixmin[row] & 0xFFFFFFFFULL);
    idxI[row] = code;
    outIdxF[row] = (float)code;
}

// ---------------------------------------------------------------- gather
// Reads ONLY d_ws (idxI) + inputs; writes the quantized region last.
__global__ __launch_bounds__(256) void vq_gather_kernel(
    const float* __restrict__ x, const float* __restrict__ cb,
    const int* __restrict__ idxI, float* __restrict__ outQ,
    float* __restrict__ partial) {
    const int wave = threadIdx.x >> 6;
    const int lane = threadIdx.x & 63;
    const int row = blockIdx.x * 4 + wave;
    const int code = idxI[row];
    const float* xr = x + (size_t)row * DIM;
    const float* er = cb + (size_t)code * DIM;
    float* qr = outQ + (size_t)row * DIM;
    float s = 0.f;
#pragma unroll
    for (int i = 0; i < 2; ++i) {
        int d = lane * 8 + i * 4;
        float4 xv = *reinterpret_cast<const float4*>(xr + d);
        float4 ev = *reinterpret_cast<const float4*>(er + d);
        float4 dv = make_float4(ev.x - xv.x, ev.y - xv.y, ev.z - xv.z, ev.w - xv.w);
        *reinterpret_cast<float4*>(qr + d) = ev;
        s += dv.x * dv.x + dv.y * dv.y + dv.z * dv.z + dv.w * dv.w;
    }
#pragma unroll
    for (int off = 32; off > 0; off >>= 1) s += __shfl_xor(s, off);
    __shared__ float ws4[4];
    if (lane == 0) ws4[wave] = s;
    __syncthreads();
    if (threadIdx.x == 0)
        partial[blockIdx.x] = (ws4[0] + ws4[1]) + (ws4[2] + ws4[3]);
}

// ---------------------------------------------------------------- loss
__global__ __launch_bounds__(256) void vq_loss_kernel(const float* __restrict__ partial,
                                                      float* __restrict__ outLoss) {
    float s = 0.f;
    for (int i = threadIdx.x; i < 8192; i += 256) s += partial[i];
    __shared__ float sm[256];
    sm[threadIdx.x] = s;
    __syncthreads();
    for (int off = 128; off > 0; off >>= 1) {
        if (threadIdx.x < off) sm[threadIdx.x] += sm[threadIdx.x + off];
        __syncthreads();
    }
    if (threadIdx.x == 0)
        outLoss[0] = sm[0] * (1.0f + BETA) / 16777216.0f;
}

// ---------------------------------------------------------------- launch
extern "C" void kernel_launch(void* const* d_in, const int* in_sizes, int n_in,
                              void* d_out, int out_size, void* d_ws, size_t ws_size,
                              hipStream_t stream) {
    const float* x = (const float*)d_in[0];   // [32768, 512]
    const float* cb = (const float*)d_in[1];  // [8192, 512]
    float* out = (float*)d_out;

    // d_out scratch (rewritten by gather at the end)
    ushortT* xh = (ushortT*)out;
    ushortT* eh = (ushortT*)(out + SC_EH_F);
    unsigned* gCode = (unsigned*)(out + SC_GCODE_F);
    unsigned* gCnt = (unsigned*)(out + SC_GCNT_F);
    unsigned long long* fixmin = (unsigned long long*)(out + SC_FIXMIN_F);
    int* fixlist = (int*)(out + SC_FIXLIST_F);

    float* xx = (float*)d_ws + WS_XX_OFF;
    int* idxI = (int*)d_ws + WS_IDX_OFF;
    float* partial = (float*)d_ws + WS_PART_OFF;
    int* fixcnt = (int*)d_ws + WS_CNT_OFF;

    hipLaunchKernelGGL(vq_init, dim3(128), dim3(256), 0, stream, gCnt, fixmin, fixcnt);
    hipLaunchKernelGGL(vq_prep, dim3(10240), dim3(256), 0, stream, x, cb, xh, eh, xx);
    hipLaunchKernelGGL(vq_margmin, dim3((N_ROWS / BM) * 2), dim3(512), 0, stream,
                       xh, eh, gCode, gCnt, fixcnt, fixlist);
    hipLaunchKernelGGL(vq_refine, dim3(N_ROWS / 4), dim3(256), 0, stream,
                       x, cb, xx, gCode, gCnt, out + IDX_OFF, idxI);
    hipLaunchKernelGGL(vq_fixup_scan, dim3(2048), dim3(256), 0, stream,
                       x, cb, xx, fixcnt, fixlist, fixmin);
    hipLaunchKernelGGL(vq_fixup_write, dim3(256), dim3(256), 0, stream,
                       fixcnt, fixlist, fixmin, out + IDX_OFF, idxI);
    hipLaunchKernelGGL(vq_gather_kernel, dim3(N_ROWS / 4), dim3(256), 0, stream,
                       x, cb, idxI, out, partial);
    hipLaunchKernelGGL(vq_loss_kernel, dim3(1), dim3(256), 0, stream,
                       partial, out + LOSS_OFF);
}